// Round 4
// baseline (459.822 us; speedup 1.0000x reference)
//
#include <hip/hip_runtime.h>
#include <math.h>

#define SDIM 8

// ======================== setup: CSR build (once per call) =================

__global__ __launch_bounds__(256) void hist_kernel(
    const int* __restrict__ eu, const int* __restrict__ ev,
    int* __restrict__ cnt, int E)
{
    int e = blockIdx.x * blockDim.x + threadIdx.x;
    if (e >= E) return;
    atomicAdd(&cnt[eu[e]], 1);
    atomicAdd(&cnt[ev[e]], 1);
}

// per-block exclusive scan, block sums to partial[]
__global__ __launch_bounds__(256) void scan1_kernel(
    const int* __restrict__ cnt, int* __restrict__ off,
    int* __restrict__ partial, int V)
{
    __shared__ int sm[256];
    int tx = threadIdx.x;
    int i = blockIdx.x * 256 + tx;
    int x = (i < V) ? cnt[i] : 0;
    int val = x;
    sm[tx] = val;
    __syncthreads();
    for (int d = 1; d < 256; d <<= 1) {
        int t = (tx >= d) ? sm[tx - d] : 0;
        __syncthreads();
        val += t;
        sm[tx] = val;
        __syncthreads();
    }
    if (i < V) off[i] = val - x;               // exclusive within block
    if (tx == 255) partial[blockIdx.x] = val;  // block total
}

// single-block exclusive scan of partials (nb <= 256)
__global__ __launch_bounds__(256) void scan2_kernel(int* __restrict__ partial, int nb)
{
    __shared__ int sm[256];
    int tx = threadIdx.x;
    int x = (tx < nb) ? partial[tx] : 0;
    int val = x;
    sm[tx] = val;
    __syncthreads();
    for (int d = 1; d < 256; d <<= 1) {
        int t = (tx >= d) ? sm[tx - d] : 0;
        __syncthreads();
        val += t;
        sm[tx] = val;
        __syncthreads();
    }
    if (tx < nb) partial[tx] = val - x;        // exclusive
}

__global__ __launch_bounds__(256) void scan3_kernel(
    int* __restrict__ off, int* __restrict__ cursor,
    const int* __restrict__ partial, int V, int total)
{
    int i = blockIdx.x * 256 + threadIdx.x;
    if (i < V) {
        int o = off[i] + partial[blockIdx.x];
        off[i] = o;
        cursor[i] = o;
    }
    if (i == 0) off[V] = total;
}

// adjacency list: adj[k] = edge-order message slot (e for dir0, E+e for dir1)
__global__ __launch_bounds__(256) void fill_kernel(
    const int* __restrict__ eu, const int* __restrict__ ev,
    int* __restrict__ cursor, int* __restrict__ adj, int E)
{
    int e = blockIdx.x * blockDim.x + threadIdx.x;
    if (e >= E) return;
    adj[atomicAdd(&cursor[eu[e]], 1)] = e;
    adj[atomicAdd(&cursor[ev[e]], 1)] = E + e;
}

// ======================== per-iteration kernels ============================

// vb[i][s] = unary[i][s] + sum over adjacency of msg[adj[k]][s]
// 8 threads per variable (one per state); msg reads are 32B coalesced per group
__global__ __launch_bounds__(256) void vb_kernel(
    const float* __restrict__ unary, const float* __restrict__ msg,
    const int* __restrict__ off, const int* __restrict__ adj,
    float* __restrict__ vb, int V)
{
    int tid = blockIdx.x * blockDim.x + threadIdx.x;
    if (tid >= V * SDIM) return;
    int i = tid >> 3, s = tid & 7;
    int b = off[i], e2 = off[i + 1];
    float acc = unary[tid];
    for (int k = b; k < e2; ++k) {
        int slot = adj[k];
        acc += msg[(size_t)slot * SDIM + s];
    }
    vb[tid] = acc;
}

// per-edge message update (max-product); messages in EDGE order (coalesced).
// __launch_bounds__(256, 1): allow high VGPR use — the kernel's live state is
// >100 floats; the default 64-VGPR budget spilled ~480 B/thread to scratch
// (the round-2/3 ~100 MB phantom WRITE_SIZE).
template<bool LAST>
__global__ __launch_bounds__(256, 1) void edge_kernel(
    const float* __restrict__ pw, const float* __restrict__ vb,
    const int* __restrict__ eu, const int* __restrict__ ev,
    const float* __restrict__ mi, float* __restrict__ mo,
    float* __restrict__ fb, int E)
{
    int e = blockIdx.x * blockDim.x + threadIdx.x;
    if (e >= E) return;
    int u = eu[e], v = ev[e];

    const float4* m0v = reinterpret_cast<const float4*>(mi + (size_t)e * SDIM);
    const float4* m1v = reinterpret_cast<const float4*>(mi + (size_t)(E + e) * SDIM);
    float4 x0 = m0v[0], x1 = m0v[1];
    float4 y0 = m1v[0], y1 = m1v[1];
    float m0r[8] = {x0.x, x0.y, x0.z, x0.w, x1.x, x1.y, x1.z, x1.w};
    float m1r[8] = {y0.x, y0.y, y0.z, y0.w, y1.x, y1.y, y1.z, y1.w};

    const float4* vu = reinterpret_cast<const float4*>(vb + (size_t)u * SDIM);
    const float4* vv = reinterpret_cast<const float4*>(vb + (size_t)v * SDIM);
    float4 u0 = vu[0], u1 = vu[1];
    float4 v0 = vv[0], v1 = vv[1];
    float vbu[8] = {u0.x, u0.y, u0.z, u0.w, u1.x, u1.y, u1.z, u1.w};
    float vbv[8] = {v0.x, v0.y, v0.z, v0.w, v1.x, v1.y, v1.z, v1.w};

    float nu[8], nv[8];
#pragma unroll
    for (int s = 0; s < 8; ++s) { nu[s] = vbu[s] - m0r[s]; nv[s] = vbv[s] - m1r[s]; }

    float nm0[8], nm1[8];
#pragma unroll
    for (int s = 0; s < 8; ++s) { nm0[s] = -INFINITY; nm1[s] = -INFINITY; }

    float vals[64];
    float fmx = -INFINITY;

    const float4* pwv = reinterpret_cast<const float4*>(pw + (size_t)e * 64);
#pragma unroll
    for (int i = 0; i < 8; ++i) {
        float4 r0 = pwv[2 * i], r1 = pwv[2 * i + 1];
        float row[8] = {r0.x, r0.y, r0.z, r0.w, r1.x, r1.y, r1.z, r1.w};
#pragma unroll
        for (int j = 0; j < 8; ++j) {
            float t = row[j];
            nm0[i] = fmaxf(nm0[i], t + nv[j]);
            nm1[j] = fmaxf(nm1[j], t + nu[i]);
            if constexpr (LAST) {
                float f = t + nu[i] + nv[j];
                vals[i * 8 + j] = f;
                fmx = fmaxf(fmx, f);
            }
        }
    }

    if constexpr (LAST) {
        float s = 0.f;
#pragma unroll
        for (int k = 0; k < 64; ++k) { float ev_ = __expf(vals[k] - fmx); vals[k] = ev_; s += ev_; }
        float inv = 1.0f / s;
        float4* fo = reinterpret_cast<float4*>(fb + (size_t)e * 64);
#pragma unroll
        for (int k = 0; k < 16; ++k)
            fo[k] = make_float4(vals[4 * k] * inv, vals[4 * k + 1] * inv,
                                vals[4 * k + 2] * inv, vals[4 * k + 3] * inv);
    }

    float mx0 = nm0[0], mx1 = nm1[0];
#pragma unroll
    for (int s = 1; s < 8; ++s) { mx0 = fmaxf(mx0, nm0[s]); mx1 = fmaxf(mx1, nm1[s]); }
    float o0[8], o1[8];
#pragma unroll
    for (int s = 0; s < 8; ++s) {
        o0[s] = 0.5f * m0r[s] + 0.5f * (nm0[s] - mx0);
        o1[s] = 0.5f * m1r[s] + 0.5f * (nm1[s] - mx1);
    }
    float4* w0 = reinterpret_cast<float4*>(mo + (size_t)e * SDIM);
    float4* w1 = reinterpret_cast<float4*>(mo + (size_t)(E + e) * SDIM);
    w0[0] = make_float4(o0[0], o0[1], o0[2], o0[3]);
    w0[1] = make_float4(o0[4], o0[5], o0[6], o0[7]);
    w1[0] = make_float4(o1[0], o1[1], o1[2], o1[3]);
    w1[1] = make_float4(o1[4], o1[5], o1[6], o1[7]);
}

// final: vb gather + softmax, 8 threads per variable, shfl_xor reduce over 8
__global__ __launch_bounds__(256) void vb_out_kernel(
    const float* __restrict__ unary, const float* __restrict__ msg,
    const int* __restrict__ off, const int* __restrict__ adj,
    float* __restrict__ out, int V)
{
    int tid = blockIdx.x * blockDim.x + threadIdx.x;
    if (tid >= V * SDIM) return;
    int i = tid >> 3;
    int b = off[i], e2 = off[i + 1];
    float acc = unary[tid];
    for (int k = b; k < e2; ++k) {
        int slot = adj[k];
        acc += msg[(size_t)slot * SDIM + (tid & 7)];
    }
    float m = acc;
    m = fmaxf(m, __shfl_xor(m, 1));
    m = fmaxf(m, __shfl_xor(m, 2));
    m = fmaxf(m, __shfl_xor(m, 4));
    float ev_ = __expf(acc - m);
    float sum = ev_;
    sum += __shfl_xor(sum, 1);
    sum += __shfl_xor(sum, 2);
    sum += __shfl_xor(sum, 4);
    out[tid] = ev_ / sum;
}

// ======================== launch ===========================================

extern "C" void kernel_launch(void* const* d_in, const int* in_sizes, int n_in,
                              void* d_out, int out_size, void* d_ws, size_t ws_size,
                              hipStream_t stream)
{
    const float* unary = (const float*)d_in[0];   // [V,8]
    const float* pw    = (const float*)d_in[1];   // [E,8,8]
    const float* initm = (const float*)d_in[2];   // [2,E,8]  (edge order)
    const int*   eidx  = (const int*)d_in[3];     // [2,E]

    int V = in_sizes[0] / SDIM;
    int E = in_sizes[3] / 2;

    const int* eu = eidx;
    const int* ev = eidx + E;

    // workspace layout
    float* msgA = (float*)d_ws;                       // [2E,8]
    float* msgB = msgA + (size_t)2 * E * SDIM;        // [2E,8]
    float* vb   = msgB + (size_t)2 * E * SDIM;        // [V,8]
    int* off    = (int*)(vb + (size_t)V * SDIM);      // [V+1]
    int* cursor = off + (V + 1);                      // [V]
    int* adj    = cursor + V;                         // [2E]
    int* partial= adj + 2 * E;                        // [256]
    int* cnt    = partial + 256;                      // [V]

    float* out_vb = (float*)d_out;
    float* out_fb = out_vb + (size_t)V * SDIM;

    int gE  = (E + 255) / 256;
    int gV8 = (V * SDIM + 255) / 256;
    int nb  = (V + 255) / 256;   // scan blocks (V=50000 -> 196 <= 256)

    // ---- build CSR (deterministic per call; no cross-call state) ----
    hipMemsetAsync(cnt, 0, (size_t)V * sizeof(int), stream);
    hist_kernel<<<gE, 256, 0, stream>>>(eu, ev, cnt, E);
    scan1_kernel<<<nb, 256, 0, stream>>>(cnt, off, partial, V);
    scan2_kernel<<<1, 256, 0, stream>>>(partial, nb);
    scan3_kernel<<<nb, 256, 0, stream>>>(off, cursor, partial, V, 2 * E);
    fill_kernel<<<gE, 256, 0, stream>>>(eu, ev, cursor, adj, E);

    // ---- 7 BP steps (1 initial + 6 scan iters; TOL gate never fires) ----
    const float* src = initm;      // initial messages are already edge-order
    for (int it = 0; it < 7; ++it) {
        float* dst = (it & 1) ? msgB : msgA;
        vb_kernel<<<gV8, 256, 0, stream>>>(unary, src, off, adj, vb, V);
        if (it < 6)
            edge_kernel<false><<<gE, 256, 0, stream>>>(pw, vb, eu, ev, src, dst, nullptr, E);
        else
            edge_kernel<true><<<gE, 256, 0, stream>>>(pw, vb, eu, ev, src, dst, out_fb, E);
        src = dst;
    }

    // ---- final var beliefs (messages after step 7) + softmax ----
    vb_out_kernel<<<gV8, 256, 0, stream>>>(unary, src, off, adj, out_vb, V);
}

// Round 5
// 403.183 us; speedup vs baseline: 1.1405x; 1.1405x over previous
//
#include <hip/hip_runtime.h>
#include <math.h>

#define SDIM 8
typedef float f32x4 __attribute__((ext_vector_type(4)));

// ======================== setup: CSR build (once per call) =================

__global__ __launch_bounds__(256) void hist_kernel(
    const int* __restrict__ eu, const int* __restrict__ ev,
    int* __restrict__ cnt, int E)
{
    int e = blockIdx.x * blockDim.x + threadIdx.x;
    if (e >= E) return;
    atomicAdd(&cnt[eu[e]], 1);
    atomicAdd(&cnt[ev[e]], 1);
}

__global__ __launch_bounds__(256) void scan1_kernel(
    const int* __restrict__ cnt, int* __restrict__ off,
    int* __restrict__ partial, int V)
{
    __shared__ int sm[256];
    int tx = threadIdx.x;
    int i = blockIdx.x * 256 + tx;
    int x = (i < V) ? cnt[i] : 0;
    int val = x;
    sm[tx] = val;
    __syncthreads();
    for (int d = 1; d < 256; d <<= 1) {
        int t = (tx >= d) ? sm[tx - d] : 0;
        __syncthreads();
        val += t;
        sm[tx] = val;
        __syncthreads();
    }
    if (i < V) off[i] = val - x;
    if (tx == 255) partial[blockIdx.x] = val;
}

__global__ __launch_bounds__(256) void scan2_kernel(int* __restrict__ partial, int nb)
{
    __shared__ int sm[256];
    int tx = threadIdx.x;
    int x = (tx < nb) ? partial[tx] : 0;
    int val = x;
    sm[tx] = val;
    __syncthreads();
    for (int d = 1; d < 256; d <<= 1) {
        int t = (tx >= d) ? sm[tx - d] : 0;
        __syncthreads();
        val += t;
        sm[tx] = val;
        __syncthreads();
    }
    if (tx < nb) partial[tx] = val - x;
}

__global__ __launch_bounds__(256) void scan3_kernel(
    int* __restrict__ off, int* __restrict__ cursor,
    const int* __restrict__ partial, int V, int total)
{
    int i = blockIdx.x * 256 + threadIdx.x;
    if (i < V) {
        int o = off[i] + partial[blockIdx.x];
        off[i] = o;
        cursor[i] = o;
    }
    if (i == 0) off[V] = total;
}

__global__ __launch_bounds__(256) void fill_kernel(
    const int* __restrict__ eu, const int* __restrict__ ev,
    int* __restrict__ cursor, int* __restrict__ adj, int E)
{
    int e = blockIdx.x * blockDim.x + threadIdx.x;
    if (e >= E) return;
    adj[atomicAdd(&cursor[eu[e]], 1)] = e;
    adj[atomicAdd(&cursor[ev[e]], 1)] = E + e;
}

// ======================== per-iteration kernels ============================

// vb[i][s] = unary[i][s] + sum over adjacency of msg[adj[k]][s]
// 8 lanes per variable; adj entries loaded 8-wide and broadcast via shfl so
// the 8 msg gathers per chunk are independent (no serial adj->msg chain).
__global__ __launch_bounds__(256) void vb_kernel(
    const float* __restrict__ unary, const float* __restrict__ msg,
    const int* __restrict__ off, const int* __restrict__ adj,
    float* __restrict__ vb, int V)
{
    int tid = blockIdx.x * blockDim.x + threadIdx.x;
    if (tid >= V * SDIM) return;
    int i = tid >> 3, s = tid & 7;
    int b = off[i], e2 = off[i + 1];
    float acc = unary[tid];
    for (int k0 = b; k0 < e2; k0 += 8) {
        int myk = k0 + s;
        int mya = (myk < e2) ? adj[myk] : 0;
        int n = e2 - k0;                 // group-uniform
#pragma unroll
        for (int t = 0; t < 8; ++t) {
            if (t < n) {
                int slot = __shfl(mya, t, 8);
                acc += msg[(size_t)slot * SDIM + s];
            }
        }
    }
    vb[tid] = acc;
}

// per-edge message update, 8 lanes per edge (lane s owns state s).
// Cross-state reductions via width-8 shuffles; ~30 VGPRs/thread, 1.6M threads.
template<bool LAST>
__global__ __launch_bounds__(256) void edge_kernel(
    const float* __restrict__ pw, const float* __restrict__ vb,
    const int* __restrict__ eu, const int* __restrict__ ev,
    const float* __restrict__ mi, float* __restrict__ mo,
    float* __restrict__ fb, int E)
{
    int tid = blockIdx.x * blockDim.x + threadIdx.x;
    int e = tid >> 3;
    if (e >= E) return;
    int s = tid & 7;

    int u = eu[e], v = ev[e];
    float m0 = mi[(size_t)e * SDIM + s];
    float m1 = mi[(size_t)(E + e) * SDIM + s];
    float bu = vb[(size_t)u * SDIM + s];
    float bv = vb[(size_t)v * SDIM + s];
    float nu = bu - m0;
    float nv = bv - m1;

    // pairwise row s (streaming, zero reuse -> nontemporal)
    const f32x4* pr = reinterpret_cast<const f32x4*>(pw + (size_t)e * 64 + s * SDIM);
    f32x4 r0 = __builtin_nontemporal_load(pr);
    f32x4 r1 = __builtin_nontemporal_load(pr + 1);
    float row[8] = {r0[0], r0[1], r0[2], r0[3], r1[0], r1[1], r1[2], r1[3]};

    // nm0[s] = max_j (pw[s][j] + nv[j])
    float nm0 = -INFINITY;
#pragma unroll
    for (int j = 0; j < 8; ++j) {
        float nvj = __shfl(nv, j, 8);
        nm0 = fmaxf(nm0, row[j] + nvj);
    }

    // t[j] = pw[s][j] + nu[s]; nm1[j] = max over lanes s of t[j]
    float t[8];
#pragma unroll
    for (int j = 0; j < 8; ++j) t[j] = row[j] + nu;
#pragma unroll
    for (int d = 1; d < 8; d <<= 1) {
#pragma unroll
        for (int j = 0; j < 8; ++j)
            t[j] = fmaxf(t[j], __shfl_xor(t[j], d, 8));
    }
    // now every lane holds the full nm1[0..7] in t[]

    if constexpr (LAST) {
        // fb[s][j] = pw[s][j] + nu[s] + nv[j]; softmax over all 64
        float f[8];
        float lmx = -INFINITY;
#pragma unroll
        for (int j = 0; j < 8; ++j) {
            float nvj = __shfl(nv, j, 8);
            f[j] = row[j] + nu + nvj;
            lmx = fmaxf(lmx, f[j]);
        }
#pragma unroll
        for (int d = 1; d < 8; d <<= 1) lmx = fmaxf(lmx, __shfl_xor(lmx, d, 8));
        float lsum = 0.f;
#pragma unroll
        for (int j = 0; j < 8; ++j) { f[j] = __expf(f[j] - lmx); lsum += f[j]; }
#pragma unroll
        for (int d = 1; d < 8; d <<= 1) lsum += __shfl_xor(lsum, d, 8);
        float inv = 1.0f / lsum;
        f32x4 o0v = {f[0] * inv, f[1] * inv, f[2] * inv, f[3] * inv};
        f32x4 o1v = {f[4] * inv, f[5] * inv, f[6] * inv, f[7] * inv};
        f32x4* fo = reinterpret_cast<f32x4*>(fb + (size_t)e * 64 + s * SDIM);
        __builtin_nontemporal_store(o0v, fo);
        __builtin_nontemporal_store(o1v, fo + 1);
    }

    // normalize: mx0 = max_s nm0[s] (butterfly); mx1 = max_j nm1[j] (in-lane)
    float mx0 = nm0;
#pragma unroll
    for (int d = 1; d < 8; d <<= 1) mx0 = fmaxf(mx0, __shfl_xor(mx0, d, 8));
    float mx1 = t[0];
#pragma unroll
    for (int j = 1; j < 8; ++j) mx1 = fmaxf(mx1, t[j]);

    // lane s needs nm1[s]: static-index select (avoid runtime array index)
    float nm1s = t[0];
#pragma unroll
    for (int j = 1; j < 8; ++j) nm1s = (s == j) ? t[j] : nm1s;

    float o0 = 0.5f * m0 + 0.5f * (nm0 - mx0);
    float o1 = 0.5f * m1 + 0.5f * (nm1s - mx1);
    mo[(size_t)e * SDIM + s] = o0;
    mo[(size_t)(E + e) * SDIM + s] = o1;
}

// final: vb gather (chunked) + softmax over the 8 states via shfl
__global__ __launch_bounds__(256) void vb_out_kernel(
    const float* __restrict__ unary, const float* __restrict__ msg,
    const int* __restrict__ off, const int* __restrict__ adj,
    float* __restrict__ out, int V)
{
    int tid = blockIdx.x * blockDim.x + threadIdx.x;
    if (tid >= V * SDIM) return;
    int i = tid >> 3, s = tid & 7;
    int b = off[i], e2 = off[i + 1];
    float acc = unary[tid];
    for (int k0 = b; k0 < e2; k0 += 8) {
        int myk = k0 + s;
        int mya = (myk < e2) ? adj[myk] : 0;
        int n = e2 - k0;
#pragma unroll
        for (int t = 0; t < 8; ++t) {
            if (t < n) {
                int slot = __shfl(mya, t, 8);
                acc += msg[(size_t)slot * SDIM + s];
            }
        }
    }
    float m = acc;
    m = fmaxf(m, __shfl_xor(m, 1, 8));
    m = fmaxf(m, __shfl_xor(m, 2, 8));
    m = fmaxf(m, __shfl_xor(m, 4, 8));
    float ev_ = __expf(acc - m);
    float sum = ev_;
    sum += __shfl_xor(sum, 1, 8);
    sum += __shfl_xor(sum, 2, 8);
    sum += __shfl_xor(sum, 4, 8);
    out[tid] = ev_ / sum;
}

// ======================== launch ===========================================

extern "C" void kernel_launch(void* const* d_in, const int* in_sizes, int n_in,
                              void* d_out, int out_size, void* d_ws, size_t ws_size,
                              hipStream_t stream)
{
    const float* unary = (const float*)d_in[0];   // [V,8]
    const float* pw    = (const float*)d_in[1];   // [E,8,8]
    const float* initm = (const float*)d_in[2];   // [2,E,8]  (edge order)
    const int*   eidx  = (const int*)d_in[3];     // [2,E]

    int V = in_sizes[0] / SDIM;
    int E = in_sizes[3] / 2;

    const int* eu = eidx;
    const int* ev = eidx + E;

    // workspace layout
    float* msgA = (float*)d_ws;                       // [2E,8]
    float* msgB = msgA + (size_t)2 * E * SDIM;        // [2E,8]
    float* vb   = msgB + (size_t)2 * E * SDIM;        // [V,8]
    int* off    = (int*)(vb + (size_t)V * SDIM);      // [V+1]
    int* cursor = off + (V + 1);                      // [V]
    int* adj    = cursor + V;                         // [2E]
    int* partial= adj + 2 * E;                        // [256]
    int* cnt    = partial + 256;                      // [V]

    float* out_vb = (float*)d_out;
    float* out_fb = out_vb + (size_t)V * SDIM;

    int gE  = (E + 255) / 256;
    int gE8 = (E * SDIM + 255) / 256;
    int gV8 = (V * SDIM + 255) / 256;
    int nb  = (V + 255) / 256;   // scan blocks (V=50000 -> 196 <= 256)

    // ---- build CSR (deterministic per call; no cross-call state) ----
    hipMemsetAsync(cnt, 0, (size_t)V * sizeof(int), stream);
    hist_kernel<<<gE, 256, 0, stream>>>(eu, ev, cnt, E);
    scan1_kernel<<<nb, 256, 0, stream>>>(cnt, off, partial, V);
    scan2_kernel<<<1, 256, 0, stream>>>(partial, nb);
    scan3_kernel<<<nb, 256, 0, stream>>>(off, cursor, partial, V, 2 * E);
    fill_kernel<<<gE, 256, 0, stream>>>(eu, ev, cursor, adj, E);

    // ---- 7 BP steps (1 initial + 6 scan iters; TOL gate never fires) ----
    const float* src = initm;      // initial messages are already edge-order
    for (int it = 0; it < 7; ++it) {
        float* dst = (it & 1) ? msgB : msgA;
        vb_kernel<<<gV8, 256, 0, stream>>>(unary, src, off, adj, vb, V);
        if (it < 6)
            edge_kernel<false><<<gE8, 256, 0, stream>>>(pw, vb, eu, ev, src, dst, nullptr, E);
        else
            edge_kernel<true><<<gE8, 256, 0, stream>>>(pw, vb, eu, ev, src, dst, out_fb, E);
        src = dst;
    }

    // ---- final var beliefs (messages after step 7) + softmax ----
    vb_out_kernel<<<gV8, 256, 0, stream>>>(unary, src, off, adj, out_vb, V);
}

// Round 7
// 372.027 us; speedup vs baseline: 1.2360x; 1.0837x over previous
//
#include <hip/hip_runtime.h>
#include <math.h>

#define SDIM 8
typedef float f32x4 __attribute__((ext_vector_type(4)));

// ======================== setup: CSR build (once per call) =================

__global__ __launch_bounds__(256) void hist_kernel(
    const int* __restrict__ eu, const int* __restrict__ ev,
    int* __restrict__ cnt, int E)
{
    int e = blockIdx.x * blockDim.x + threadIdx.x;
    if (e >= E) return;
    atomicAdd(&cnt[eu[e]], 1);
    atomicAdd(&cnt[ev[e]], 1);
}

__global__ __launch_bounds__(256) void scan1_kernel(
    const int* __restrict__ cnt, int* __restrict__ off,
    int* __restrict__ partial, int V)
{
    __shared__ int sm[256];
    int tx = threadIdx.x;
    int i = blockIdx.x * 256 + tx;
    int x = (i < V) ? cnt[i] : 0;
    int val = x;
    sm[tx] = val;
    __syncthreads();
    for (int d = 1; d < 256; d <<= 1) {
        int t = (tx >= d) ? sm[tx - d] : 0;
        __syncthreads();
        val += t;
        sm[tx] = val;
        __syncthreads();
    }
    if (i < V) off[i] = val - x;
    if (tx == 255) partial[blockIdx.x] = val;
}

__global__ __launch_bounds__(256) void scan2_kernel(int* __restrict__ partial, int nb)
{
    __shared__ int sm[256];
    int tx = threadIdx.x;
    int x = (tx < nb) ? partial[tx] : 0;
    int val = x;
    sm[tx] = val;
    __syncthreads();
    for (int d = 1; d < 256; d <<= 1) {
        int t = (tx >= d) ? sm[tx - d] : 0;
        __syncthreads();
        val += t;
        sm[tx] = val;
        __syncthreads();
    }
    if (tx < nb) partial[tx] = val - x;
}

__global__ __launch_bounds__(256) void scan3_kernel(
    int* __restrict__ off, int* __restrict__ cursor,
    const int* __restrict__ partial, int V, int total)
{
    int i = blockIdx.x * 256 + threadIdx.x;
    if (i < V) {
        int o = off[i] + partial[blockIdx.x];
        off[i] = o;
        cursor[i] = o;
    }
    if (i == 0) off[V] = total;
}

__global__ __launch_bounds__(256) void fill_kernel(
    const int* __restrict__ eu, const int* __restrict__ ev,
    int* __restrict__ cursor, int* __restrict__ adj, int E)
{
    int e = blockIdx.x * blockDim.x + threadIdx.x;
    if (e >= E) return;
    adj[atomicAdd(&cursor[eu[e]], 1)] = e;
    adj[atomicAdd(&cursor[ev[e]], 1)] = E + e;
}

// ======================== per-iteration kernels ============================

// vb[i][s] = unary[i][s] + sum over adjacency of msg[adj[k]][s]
// 8 lanes per variable; adj entries loaded 8-wide and broadcast via shfl so
// the 8 msg gathers per chunk are independent. Full chunks run unguarded.
__global__ __launch_bounds__(256) void vb_kernel(
    const float* __restrict__ unary, const float* __restrict__ msg,
    const int* __restrict__ off, const int* __restrict__ adj,
    float* __restrict__ vb, int V)
{
    int tid = blockIdx.x * blockDim.x + threadIdx.x;
    if (tid >= V * SDIM) return;
    int i = tid >> 3, s = tid & 7;
    int b = off[i], e2 = off[i + 1];
    float acc = unary[tid];
    int k0 = b;
    for (; k0 + 8 <= e2; k0 += 8) {        // full chunks, no guards
        int mya = adj[k0 + s];
#pragma unroll
        for (int t = 0; t < 8; ++t) {
            int slot = __shfl(mya, t, 8);
            acc += msg[(size_t)slot * SDIM + s];
        }
    }
    if (k0 < e2) {                          // tail chunk
        int myk = k0 + s;
        int mya = (myk < e2) ? adj[myk] : 0;
        int n = e2 - k0;
#pragma unroll
        for (int t = 0; t < 8; ++t) {
            if (t < n) {
                int slot = __shfl(mya, t, 8);
                acc += msg[(size_t)slot * SDIM + s];
            }
        }
    }
    vb[tid] = acc;
}

// per-edge message update, 8 lanes per edge (lane s owns state s).
// pw loads are PLAIN (not nontemporal): working set ~135 MB fits the 256 MB
// L3, so pw should be L3-resident after the first iteration. fb stores stay
// nontemporal (write-once output; keep it out of L3).
template<bool LAST>
__global__ __launch_bounds__(256) void edge_kernel(
    const float* __restrict__ pw, const float* __restrict__ vb,
    const int* __restrict__ eu, const int* __restrict__ ev,
    const float* __restrict__ mi, float* __restrict__ mo,
    float* __restrict__ fb, int E)
{
    int tid = blockIdx.x * blockDim.x + threadIdx.x;
    int e = tid >> 3;
    if (e >= E) return;
    int s = tid & 7;

    int u = eu[e], v = ev[e];
    float m0 = mi[(size_t)e * SDIM + s];
    float m1 = mi[(size_t)(E + e) * SDIM + s];
    float bu = vb[(size_t)u * SDIM + s];
    float bv = vb[(size_t)v * SDIM + s];
    float nu = bu - m0;
    float nv = bv - m1;

    const f32x4* pr = reinterpret_cast<const f32x4*>(pw + (size_t)e * 64 + s * SDIM);
    f32x4 r0 = pr[0];
    f32x4 r1 = pr[1];
    float row[8] = {r0[0], r0[1], r0[2], r0[3], r1[0], r1[1], r1[2], r1[3]};

    // nm0[s] = max_j (pw[s][j] + nv[j])
    float nm0 = -INFINITY;
#pragma unroll
    for (int j = 0; j < 8; ++j) {
        float nvj = __shfl(nv, j, 8);
        nm0 = fmaxf(nm0, row[j] + nvj);
    }

    // t[j] = pw[s][j] + nu[s]; nm1[j] = max over lanes s of t[j]
    float t[8];
#pragma unroll
    for (int j = 0; j < 8; ++j) t[j] = row[j] + nu;
#pragma unroll
    for (int d = 1; d < 8; d <<= 1) {
#pragma unroll
        for (int j = 0; j < 8; ++j)
            t[j] = fmaxf(t[j], __shfl_xor(t[j], d, 8));
    }
    // every lane now holds the full nm1[0..7] in t[]

    if constexpr (LAST) {
        float f[8];
        float lmx = -INFINITY;
#pragma unroll
        for (int j = 0; j < 8; ++j) {
            float nvj = __shfl(nv, j, 8);
            f[j] = row[j] + nu + nvj;
            lmx = fmaxf(lmx, f[j]);
        }
#pragma unroll
        for (int d = 1; d < 8; d <<= 1) lmx = fmaxf(lmx, __shfl_xor(lmx, d, 8));
        float lsum = 0.f;
#pragma unroll
        for (int j = 0; j < 8; ++j) { f[j] = __expf(f[j] - lmx); lsum += f[j]; }
#pragma unroll
        for (int d = 1; d < 8; d <<= 1) lsum += __shfl_xor(lsum, d, 8);
        float inv = 1.0f / lsum;
        f32x4 o0v = {f[0] * inv, f[1] * inv, f[2] * inv, f[3] * inv};
        f32x4 o1v = {f[4] * inv, f[5] * inv, f[6] * inv, f[7] * inv};
        f32x4* fo = reinterpret_cast<f32x4*>(fb + (size_t)e * 64 + s * SDIM);
        __builtin_nontemporal_store(o0v, fo);
        __builtin_nontemporal_store(o1v, fo + 1);
    }

    // normalize: mx0 = max_s nm0[s] (butterfly); mx1 = max_j nm1[j] (in-lane)
    float mx0 = nm0;
#pragma unroll
    for (int d = 1; d < 8; d <<= 1) mx0 = fmaxf(mx0, __shfl_xor(mx0, d, 8));
    float mx1 = t[0];
#pragma unroll
    for (int j = 1; j < 8; ++j) mx1 = fmaxf(mx1, t[j]);

    // lane s needs nm1[s]: static-index select
    float nm1s = t[0];
#pragma unroll
    for (int j = 1; j < 8; ++j) nm1s = (s == j) ? t[j] : nm1s;

    float o0 = 0.5f * m0 + 0.5f * (nm0 - mx0);
    float o1 = 0.5f * m1 + 0.5f * (nm1s - mx1);
    mo[(size_t)e * SDIM + s] = o0;
    mo[(size_t)(E + e) * SDIM + s] = o1;
}

// final: vb gather (chunked) + softmax over the 8 states via shfl
__global__ __launch_bounds__(256) void vb_out_kernel(
    const float* __restrict__ unary, const float* __restrict__ msg,
    const int* __restrict__ off, const int* __restrict__ adj,
    float* __restrict__ out, int V)
{
    int tid = blockIdx.x * blockDim.x + threadIdx.x;
    if (tid >= V * SDIM) return;
    int i = tid >> 3, s = tid & 7;
    int b = off[i], e2 = off[i + 1];
    float acc = unary[tid];
    int k0 = b;
    for (; k0 + 8 <= e2; k0 += 8) {
        int mya = adj[k0 + s];
#pragma unroll
        for (int t = 0; t < 8; ++t) {
            int slot = __shfl(mya, t, 8);
            acc += msg[(size_t)slot * SDIM + s];
        }
    }
    if (k0 < e2) {
        int myk = k0 + s;
        int mya = (myk < e2) ? adj[myk] : 0;
        int n = e2 - k0;
#pragma unroll
        for (int t = 0; t < 8; ++t) {
            if (t < n) {
                int slot = __shfl(mya, t, 8);
                acc += msg[(size_t)slot * SDIM + s];
            }
        }
    }
    float m = acc;
    m = fmaxf(m, __shfl_xor(m, 1, 8));
    m = fmaxf(m, __shfl_xor(m, 2, 8));
    m = fmaxf(m, __shfl_xor(m, 4, 8));
    float ev_ = __expf(acc - m);
    float sum = ev_;
    sum += __shfl_xor(sum, 1, 8);
    sum += __shfl_xor(sum, 2, 8);
    sum += __shfl_xor(sum, 4, 8);
    out[tid] = ev_ / sum;
}

// ======================== launch ===========================================

extern "C" void kernel_launch(void* const* d_in, const int* in_sizes, int n_in,
                              void* d_out, int out_size, void* d_ws, size_t ws_size,
                              hipStream_t stream)
{
    const float* unary = (const float*)d_in[0];   // [V,8]
    const float* pw    = (const float*)d_in[1];   // [E,8,8]
    const float* initm = (const float*)d_in[2];   // [2,E,8]  (edge order)
    const int*   eidx  = (const int*)d_in[3];     // [2,E]

    int V = in_sizes[0] / SDIM;
    int E = in_sizes[3] / 2;

    const int* eu = eidx;
    const int* ev = eidx + E;

    // workspace layout
    float* msgA = (float*)d_ws;                       // [2E,8]
    float* msgB = msgA + (size_t)2 * E * SDIM;        // [2E,8]
    float* vb   = msgB + (size_t)2 * E * SDIM;        // [V,8]
    int* off    = (int*)(vb + (size_t)V * SDIM);      // [V+1]
    int* cursor = off + (V + 1);                      // [V]
    int* adj    = cursor + V;                         // [2E]
    int* partial= adj + 2 * E;                        // [256]
    int* cnt    = partial + 256;                      // [V]

    float* out_vb = (float*)d_out;
    float* out_fb = out_vb + (size_t)V * SDIM;

    int gE  = (E + 255) / 256;
    int gE8 = (E * SDIM + 255) / 256;
    int gV8 = (V * SDIM + 255) / 256;
    int nb  = (V + 255) / 256;   // scan blocks (V=50000 -> 196 <= 256)

    // ---- build CSR (deterministic per call; no cross-call state) ----
    hipMemsetAsync(cnt, 0, (size_t)V * sizeof(int), stream);
    hist_kernel<<<gE, 256, 0, stream>>>(eu, ev, cnt, E);
    scan1_kernel<<<nb, 256, 0, stream>>>(cnt, off, partial, V);
    scan2_kernel<<<1, 256, 0, stream>>>(partial, nb);
    scan3_kernel<<<nb, 256, 0, stream>>>(off, cursor, partial, V, 2 * E);
    fill_kernel<<<gE, 256, 0, stream>>>(eu, ev, cursor, adj, E);

    // ---- 7 BP steps (1 initial + 6 scan iters; TOL gate never fires) ----
    const float* src = initm;      // initial messages are already edge-order
    for (int it = 0; it < 7; ++it) {
        float* dst = (it & 1) ? msgB : msgA;
        vb_kernel<<<gV8, 256, 0, stream>>>(unary, src, off, adj, vb, V);
        if (it < 6)
            edge_kernel<false><<<gE8, 256, 0, stream>>>(pw, vb, eu, ev, src, dst, nullptr, E);
        else
            edge_kernel<true><<<gE8, 256, 0, stream>>>(pw, vb, eu, ev, src, dst, out_fb, E);
        src = dst;
    }

    // ---- final var beliefs (messages after step 7) + softmax ----
    vb_out_kernel<<<gV8, 256, 0, stream>>>(unary, src, off, adj, out_vb, V);
}

// Round 8
// 370.143 us; speedup vs baseline: 1.2423x; 1.0051x over previous
//
#include <hip/hip_runtime.h>
#include <math.h>

#define SDIM 8
typedef float f32x4 __attribute__((ext_vector_type(4)));
typedef _Float16 f16x8 __attribute__((ext_vector_type(8)));

// ======================== setup: CSR build (once per call) =================

__global__ __launch_bounds__(256) void hist_kernel(
    const int* __restrict__ eu, const int* __restrict__ ev,
    int* __restrict__ cnt, int E)
{
    int e = blockIdx.x * blockDim.x + threadIdx.x;
    if (e >= E) return;
    atomicAdd(&cnt[eu[e]], 1);
    atomicAdd(&cnt[ev[e]], 1);
}

__global__ __launch_bounds__(256) void scan1_kernel(
    const int* __restrict__ cnt, int* __restrict__ off,
    int* __restrict__ partial, int V)
{
    __shared__ int sm[256];
    int tx = threadIdx.x;
    int i = blockIdx.x * 256 + tx;
    int x = (i < V) ? cnt[i] : 0;
    int val = x;
    sm[tx] = val;
    __syncthreads();
    for (int d = 1; d < 256; d <<= 1) {
        int t = (tx >= d) ? sm[tx - d] : 0;
        __syncthreads();
        val += t;
        sm[tx] = val;
        __syncthreads();
    }
    if (i < V) off[i] = val - x;
    if (tx == 255) partial[blockIdx.x] = val;
}

__global__ __launch_bounds__(256) void scan2_kernel(int* __restrict__ partial, int nb)
{
    __shared__ int sm[256];
    int tx = threadIdx.x;
    int x = (tx < nb) ? partial[tx] : 0;
    int val = x;
    sm[tx] = val;
    __syncthreads();
    for (int d = 1; d < 256; d <<= 1) {
        int t = (tx >= d) ? sm[tx - d] : 0;
        __syncthreads();
        val += t;
        sm[tx] = val;
        __syncthreads();
    }
    if (tx < nb) partial[tx] = val - x;
}

__global__ __launch_bounds__(256) void scan3_kernel(
    int* __restrict__ off, int* __restrict__ cursor,
    const int* __restrict__ partial, int V, int total)
{
    int i = blockIdx.x * 256 + threadIdx.x;
    if (i < V) {
        int o = off[i] + partial[blockIdx.x];
        off[i] = o;
        cursor[i] = o;
    }
    if (i == 0) off[V] = total;
}

__global__ __launch_bounds__(256) void fill_kernel(
    const int* __restrict__ eu, const int* __restrict__ ev,
    int* __restrict__ cursor, int* __restrict__ adj, int E)
{
    int e = blockIdx.x * blockDim.x + threadIdx.x;
    if (e >= E) return;
    adj[atomicAdd(&cursor[eu[e]], 1)] = e;
    adj[atomicAdd(&cursor[ev[e]], 1)] = E + e;
}

// one-time pairwise fp32 -> fp16 compression (halves the 7x-read stream).
// NT read (fp32 pw never touched again); PLAIN store (want pwh cache-resident).
__global__ __launch_bounds__(256) void cvt_pw_kernel(
    const float* __restrict__ pw, _Float16* __restrict__ pwh, long n8)
{
    long t = (long)blockIdx.x * blockDim.x + threadIdx.x;
    if (t >= n8) return;
    const f32x4* src = reinterpret_cast<const f32x4*>(pw + t * 8);
    f32x4 a = __builtin_nontemporal_load(src);
    f32x4 b = __builtin_nontemporal_load(src + 1);
    f16x8 o = {(_Float16)a[0], (_Float16)a[1], (_Float16)a[2], (_Float16)a[3],
               (_Float16)b[0], (_Float16)b[1], (_Float16)b[2], (_Float16)b[3]};
    *reinterpret_cast<f16x8*>(pwh + t * 8) = o;
}

// ======================== per-iteration kernels ============================

// vb[i][s] = unary[i][s] + sum over adjacency of msg[adj[k]][s]
__global__ __launch_bounds__(256) void vb_kernel(
    const float* __restrict__ unary, const float* __restrict__ msg,
    const int* __restrict__ off, const int* __restrict__ adj,
    float* __restrict__ vb, int V)
{
    int tid = blockIdx.x * blockDim.x + threadIdx.x;
    if (tid >= V * SDIM) return;
    int i = tid >> 3, s = tid & 7;
    int b = off[i], e2 = off[i + 1];
    float acc = unary[tid];
    int k0 = b;
    for (; k0 + 8 <= e2; k0 += 8) {        // full chunks, no guards
        int mya = adj[k0 + s];
#pragma unroll
        for (int t = 0; t < 8; ++t) {
            int slot = __shfl(mya, t, 8);
            acc += msg[(size_t)slot * SDIM + s];
        }
    }
    if (k0 < e2) {                          // tail chunk
        int myk = k0 + s;
        int mya = (myk < e2) ? adj[myk] : 0;
        int n = e2 - k0;
#pragma unroll
        for (int t = 0; t < 8; ++t) {
            if (t < n) {
                int slot = __shfl(mya, t, 8);
                acc += msg[(size_t)slot * SDIM + s];
            }
        }
    }
    vb[tid] = acc;
}

// per-edge message update, 8 lanes per edge (lane s owns state s).
// pairwise read as fp16 (half the bytes of the dominant stream).
template<bool LAST>
__global__ __launch_bounds__(256) void edge_kernel(
    const _Float16* __restrict__ pwh, const float* __restrict__ vb,
    const int* __restrict__ eu, const int* __restrict__ ev,
    const float* __restrict__ mi, float* __restrict__ mo,
    float* __restrict__ fb, int E)
{
    int tid = blockIdx.x * blockDim.x + threadIdx.x;
    int e = tid >> 3;
    if (e >= E) return;
    int s = tid & 7;

    int u = eu[e], v = ev[e];
    float m0 = mi[(size_t)e * SDIM + s];
    float m1 = mi[(size_t)(E + e) * SDIM + s];
    float bu = vb[(size_t)u * SDIM + s];
    float bv = vb[(size_t)v * SDIM + s];
    float nu = bu - m0;
    float nv = bv - m1;

    f16x8 rh = *reinterpret_cast<const f16x8*>(pwh + (size_t)e * 64 + s * SDIM);
    float row[8];
#pragma unroll
    for (int j = 0; j < 8; ++j) row[j] = (float)rh[j];

    // nm0[s] = max_j (pw[s][j] + nv[j])
    float nm0 = -INFINITY;
#pragma unroll
    for (int j = 0; j < 8; ++j) {
        float nvj = __shfl(nv, j, 8);
        nm0 = fmaxf(nm0, row[j] + nvj);
    }

    // t[j] = pw[s][j] + nu[s]; nm1[j] = max over lanes s of t[j]
    float t[8];
#pragma unroll
    for (int j = 0; j < 8; ++j) t[j] = row[j] + nu;
#pragma unroll
    for (int d = 1; d < 8; d <<= 1) {
#pragma unroll
        for (int j = 0; j < 8; ++j)
            t[j] = fmaxf(t[j], __shfl_xor(t[j], d, 8));
    }
    // every lane now holds the full nm1[0..7] in t[]

    if constexpr (LAST) {
        float f[8];
        float lmx = -INFINITY;
#pragma unroll
        for (int j = 0; j < 8; ++j) {
            float nvj = __shfl(nv, j, 8);
            f[j] = row[j] + nu + nvj;
            lmx = fmaxf(lmx, f[j]);
        }
#pragma unroll
        for (int d = 1; d < 8; d <<= 1) lmx = fmaxf(lmx, __shfl_xor(lmx, d, 8));
        float lsum = 0.f;
#pragma unroll
        for (int j = 0; j < 8; ++j) { f[j] = __expf(f[j] - lmx); lsum += f[j]; }
#pragma unroll
        for (int d = 1; d < 8; d <<= 1) lsum += __shfl_xor(lsum, d, 8);
        float inv = 1.0f / lsum;
        f32x4 o0v = {f[0] * inv, f[1] * inv, f[2] * inv, f[3] * inv};
        f32x4 o1v = {f[4] * inv, f[5] * inv, f[6] * inv, f[7] * inv};
        f32x4* fo = reinterpret_cast<f32x4*>(fb + (size_t)e * 64 + s * SDIM);
        __builtin_nontemporal_store(o0v, fo);
        __builtin_nontemporal_store(o1v, fo + 1);
    }

    // normalize: mx0 = max_s nm0[s] (butterfly); mx1 = max_j nm1[j] (in-lane)
    float mx0 = nm0;
#pragma unroll
    for (int d = 1; d < 8; d <<= 1) mx0 = fmaxf(mx0, __shfl_xor(mx0, d, 8));
    float mx1 = t[0];
#pragma unroll
    for (int j = 1; j < 8; ++j) mx1 = fmaxf(mx1, t[j]);

    // lane s needs nm1[s]: static-index select
    float nm1s = t[0];
#pragma unroll
    for (int j = 1; j < 8; ++j) nm1s = (s == j) ? t[j] : nm1s;

    float o0 = 0.5f * m0 + 0.5f * (nm0 - mx0);
    float o1 = 0.5f * m1 + 0.5f * (nm1s - mx1);
    mo[(size_t)e * SDIM + s] = o0;
    mo[(size_t)(E + e) * SDIM + s] = o1;
}

// final: vb gather (chunked) + softmax over the 8 states via shfl
__global__ __launch_bounds__(256) void vb_out_kernel(
    const float* __restrict__ unary, const float* __restrict__ msg,
    const int* __restrict__ off, const int* __restrict__ adj,
    float* __restrict__ out, int V)
{
    int tid = blockIdx.x * blockDim.x + threadIdx.x;
    if (tid >= V * SDIM) return;
    int i = tid >> 3, s = tid & 7;
    int b = off[i], e2 = off[i + 1];
    float acc = unary[tid];
    int k0 = b;
    for (; k0 + 8 <= e2; k0 += 8) {
        int mya = adj[k0 + s];
#pragma unroll
        for (int t = 0; t < 8; ++t) {
            int slot = __shfl(mya, t, 8);
            acc += msg[(size_t)slot * SDIM + s];
        }
    }
    if (k0 < e2) {
        int myk = k0 + s;
        int mya = (myk < e2) ? adj[myk] : 0;
        int n = e2 - k0;
#pragma unroll
        for (int t = 0; t < 8; ++t) {
            if (t < n) {
                int slot = __shfl(mya, t, 8);
                acc += msg[(size_t)slot * SDIM + s];
            }
        }
    }
    float m = acc;
    m = fmaxf(m, __shfl_xor(m, 1, 8));
    m = fmaxf(m, __shfl_xor(m, 2, 8));
    m = fmaxf(m, __shfl_xor(m, 4, 8));
    float ev_ = __expf(acc - m);
    float sum = ev_;
    sum += __shfl_xor(sum, 1, 8);
    sum += __shfl_xor(sum, 2, 8);
    sum += __shfl_xor(sum, 4, 8);
    out[tid] = ev_ / sum;
}

// ======================== launch ===========================================

extern "C" void kernel_launch(void* const* d_in, const int* in_sizes, int n_in,
                              void* d_out, int out_size, void* d_ws, size_t ws_size,
                              hipStream_t stream)
{
    const float* unary = (const float*)d_in[0];   // [V,8]
    const float* pw    = (const float*)d_in[1];   // [E,8,8]
    const float* initm = (const float*)d_in[2];   // [2,E,8]  (edge order)
    const int*   eidx  = (const int*)d_in[3];     // [2,E]

    int V = in_sizes[0] / SDIM;
    int E = in_sizes[3] / 2;

    const int* eu = eidx;
    const int* ev = eidx + E;

    // workspace layout (16B-aligned sections)
    float* msgA = (float*)d_ws;                         // [2E*8] f32
    float* msgB = msgA + (size_t)2 * E * SDIM;          // [2E*8] f32
    float* vb   = msgB + (size_t)2 * E * SDIM;          // [V*8]  f32
    _Float16* pwh = (_Float16*)(vb + (size_t)V * SDIM); // [E*64] f16
    int* off    = (int*)(pwh + (size_t)E * 64);         // [V+1]
    int* cursor = off + (V + 1);                        // [V]
    int* adj    = cursor + V;                           // [2E]
    int* partial= adj + 2 * E;                          // [256]
    int* cnt    = partial + 256;                        // [V]

    float* out_vb = (float*)d_out;
    float* out_fb = out_vb + (size_t)V * SDIM;

    int gE  = (E + 255) / 256;
    int gE8 = (E * SDIM + 255) / 256;
    int gV8 = (V * SDIM + 255) / 256;
    int nb  = (V + 255) / 256;   // scan blocks (V=50000 -> 196 <= 256)

    // ---- one-time pw fp16 compression + CSR build ----
    cvt_pw_kernel<<<gE8, 256, 0, stream>>>(pw, pwh, (long)E * SDIM);
    hipMemsetAsync(cnt, 0, (size_t)V * sizeof(int), stream);
    hist_kernel<<<gE, 256, 0, stream>>>(eu, ev, cnt, E);
    scan1_kernel<<<nb, 256, 0, stream>>>(cnt, off, partial, V);
    scan2_kernel<<<1, 256, 0, stream>>>(partial, nb);
    scan3_kernel<<<nb, 256, 0, stream>>>(off, cursor, partial, V, 2 * E);
    fill_kernel<<<gE, 256, 0, stream>>>(eu, ev, cursor, adj, E);

    // ---- 7 BP steps (1 initial + 6 scan iters; TOL gate never fires) ----
    const float* src = initm;      // initial messages are already edge-order
    for (int it = 0; it < 7; ++it) {
        float* dst = (it & 1) ? msgB : msgA;
        vb_kernel<<<gV8, 256, 0, stream>>>(unary, src, off, adj, vb, V);
        if (it < 6)
            edge_kernel<false><<<gE8, 256, 0, stream>>>(pwh, vb, eu, ev, src, dst, nullptr, E);
        else
            edge_kernel<true><<<gE8, 256, 0, stream>>>(pwh, vb, eu, ev, src, dst, out_fb, E);
        src = dst;
    }

    // ---- final var beliefs (messages after step 7) + softmax ----
    vb_out_kernel<<<gV8, 256, 0, stream>>>(unary, src, off, adj, out_vb, V);
}